// Round 7
// baseline (121.761 us; speedup 1.0000x reference)
//
#include <hip/hip_runtime.h>

#define NN 4096
#define FIN 256
#define FOUT 64
#define NH 4
#define NSPLIT 4

using f32x4 = __attribute__((ext_vector_type(4))) float;
using s16x8 = __attribute__((ext_vector_type(8))) short;
typedef unsigned long long u64;

__device__ __forceinline__ unsigned short f32_to_bf16_rne(float f) {
    unsigned b = __float_as_uint(f);
    b += 0x7FFFu + ((b >> 16) & 1u);
    return (unsigned short)(b >> 16);
}

// Kernel A: Wh[h] = x @ W[h] via bf16 MFMA -> WhT bf16 [H][FOUT][NN]; s1,s2 (pre-scaled log2e)
__global__ __launch_bounds__(256) void k_wh(
    const float* __restrict__ x, const float* __restrict__ W,
    const float* __restrict__ a, short* __restrict__ WhT,
    float* __restrict__ s1, float* __restrict__ s2)
{
    __shared__ unsigned short xs[64 * 256];   // bf16 x-tile, XOR-swizzled (16B granule), 32 KB
    __shared__ unsigned short wt[64 * 256];   // bf16 W^T [o][f], XOR-swizzled, 32 KB
    const int nb = blockIdx.x, h = blockIdx.y, t = threadIdx.x;
    const int n0 = nb * 64;
    {
        const float4* xg = reinterpret_cast<const float4*>(x + (size_t)n0 * FIN);
        for (int k = t; k < 64 * FIN / 4; k += 256) {
            float4 v = xg[k];
            int row = k >> 6, fq = k & 63;
            u64 pk = (u64)f32_to_bf16_rne(v.x) | ((u64)f32_to_bf16_rne(v.y) << 16)
                   | ((u64)f32_to_bf16_rne(v.z) << 32) | ((u64)f32_to_bf16_rne(v.w) << 48);
            int byte = (row * 512 + fq * 8) ^ ((row & 7) << 4);
            *(u64*)((char*)xs + byte) = pk;
        }
        const float* Wg = W + (size_t)h * FIN * FOUT;
        for (int k = t; k < FIN * FOUT; k += 256) {
            int f = k >> 6, o = k & 63;
            unsigned short wv = f32_to_bf16_rne(Wg[k]);
            int byte = (o * 512 + f * 2) ^ ((o & 7) << 4);
            *(unsigned short*)((char*)wt + byte) = wv;
        }
    }
    __syncthreads();
    const int lane = t & 63, wv_ = t >> 6;
    const int rowA = lane & 15;
    const int kq = (lane >> 4) * 8;
    const int i0 = wv_ * 16;
    f32x4 acc[4];
    #pragma unroll
    for (int c = 0; c < 4; ++c) acc[c] = (f32x4){0.f, 0.f, 0.f, 0.f};
    const int arow = i0 + rowA;
    #pragma unroll
    for (int kb = 0; kb < FIN; kb += 32) {
        int ab = (arow * 512 + (kb + kq) * 2) ^ ((arow & 7) << 4);
        s16x8 af = *(const s16x8*)((char*)xs + ab);
        #pragma unroll
        for (int c = 0; c < 4; ++c) {
            int col = c * 16 + rowA;
            int bb = (col * 512 + (kb + kq) * 2) ^ ((col & 7) << 4);
            s16x8 bf = *(const s16x8*)((char*)wt + bb);
            acc[c] = __builtin_amdgcn_mfma_f32_16x16x32_bf16(af, bf, acc[c], 0, 0, 0);
        }
    }
    const int q0 = (lane >> 4) * 4;
    const float L2E = 1.4426950408889634f;
    float v1acc[4] = {0.f, 0.f, 0.f, 0.f}, v2acc[4] = {0.f, 0.f, 0.f, 0.f};
    #pragma unroll
    for (int c = 0; c < 4; ++c) {
        int col = c * 16 + rowA;
        float a1v = a[h * (2 * FOUT) + col];
        float a2v = a[h * (2 * FOUT) + FOUT + col];
        short* wp = WhT + ((size_t)(h * FOUT + col)) * NN + n0 + i0 + q0;
        alignas(8) unsigned short tmp[4];
        #pragma unroll
        for (int q = 0; q < 4; ++q) {
            float v = acc[c][q];
            tmp[q] = f32_to_bf16_rne(v);
            v1acc[q] = fmaf(v, a1v, v1acc[q]);
            v2acc[q] = fmaf(v, a2v, v2acc[q]);
        }
        __builtin_memcpy(wp, tmp, 8);
    }
    #pragma unroll
    for (int q = 0; q < 4; ++q) {
        float v1 = v1acc[q] * L2E, v2 = v2acc[q] * L2E;
        #pragma unroll
        for (int d = 1; d < 16; d <<= 1) {
            v1 += __shfl_xor(v1, d, 64);
            v2 += __shfl_xor(v2, d, 64);
        }
        if (rowA == 0) {
            int n = n0 + i0 + q0 + q;
            s1[h * NN + n] = v1;
            s2[h * NN + n] = v2;
        }
    }
}

// Kernel B: per-row constants c1 = s1 - M, c2 = 0.2*s1 - M  (M = LeakyReLU(s1 + max_j s2))
__global__ __launch_bounds__(256) void k_prep(
    const float* __restrict__ s1, const float* __restrict__ s2,
    float* __restrict__ c1g, float* __restrict__ c2g)
{
    const int t = threadIdx.x;
    const int idx = blockIdx.x * 256 + t;      // over NH*NN
    const int h = idx >> 12;
    __shared__ float red[256];
    const float* s2p = s2 + (h << 12);
    float m = -1e30f;
    for (int j = t; j < NN; j += 256) m = fmaxf(m, s2p[j]);
    red[t] = m;
    __syncthreads();
    for (int st = 128; st > 0; st >>= 1) {
        if (t < st) red[t] = fmaxf(red[t], red[t + st]);
        __syncthreads();
    }
    float s2mv = red[0];
    float v = s1[idx];
    float tt = v + s2mv;
    float M = fmaxf(tt, 0.2f * tt);
    c1g[idx] = v - M;
    c2g[idx] = fmaf(0.2f, v, -M);
}

// Kernel C: fused masked-softmax + PV, P built ENTIRELY in registers in the
// MFMA A-fragment layout (lane 16g+r computes P[r][8g+q], q=0..7, per frag).
// No LDS, no scalar mask loads -> no lgkmcnt serialization. adj read raw
// (each element exactly once chip-wide), 1-deep prefetched against HBM latency.
__global__ __launch_bounds__(256, 4) void k_attn(
    const int* __restrict__ adj, const short* __restrict__ WhT,
    const float* __restrict__ c1g, const float* __restrict__ c2g,
    const float* __restrict__ s2,
    float* __restrict__ ws_acc, float* __restrict__ ws_l)
{
    const int t = threadIdx.x;
    const int lane = t & 63;
    const int h = __builtin_amdgcn_readfirstlane(t >> 6);
    const int ib = blockIdx.x;
    const int s = blockIdx.y;
    const int i0 = ib * 16;
    const int row16 = lane & 15;
    const int kbase = (lane >> 4) * 8;

    // per-lane row constants (this lane only ever scores row i0+row16)
    const float c1v = c1g[h * NN + i0 + row16];
    const float c2v = c2g[h * NN + i0 + row16];

    f32x4 acc[4], acc_l;
    #pragma unroll
    for (int c = 0; c < 4; ++c) acc[c] = (f32x4){0.f, 0.f, 0.f, 0.f};
    acc_l = (f32x4){0.f, 0.f, 0.f, 0.f};
    s16x8 ones;
    #pragma unroll
    for (int i = 0; i < 8; ++i) ones[i] = (short)0x3F80;   // bf16 1.0

    const float* s2q = s2 + h * NN + kbase;                      // + jb + {0,4,32,36}
    const int*   ap  = adj + (size_t)(i0 + row16) * NN + kbase;  // + jb + {0,4,32,36}
    const short* bbase = WhT + (size_t)h * FOUT * NN + (size_t)row16 * NN + kbase;

    // one packed A-dword from 2 scores
    auto mk = [&](float sa, float sb, int aa, int ab) -> unsigned {
        float e0 = fmaxf(c1v + sa, fmaf(0.2f, sa, c2v));
        float e1 = fmaxf(c1v + sb, fmaf(0.2f, sb, c2v));
        float p0 = __builtin_amdgcn_exp2f(e0);
        float p1 = __builtin_amdgcn_exp2f(e1);
        p0 = (aa > 0) ? p0 : 0.f;
        p1 = (ab > 0) ? p1 : 0.f;
        unsigned pk;
        asm("v_cvt_pk_bf16_f32 %0, %1, %2" : "=v"(pk) : "v"(p0), "v"(p1));
        return pk;
    };

    auto body = [&](int jb, int4 (&ca)[4], int4 (&na)[4]) {
        // prefetch NEXT iter's adj (the only HBM stream) first
        int jn = jb + NSPLIT * 64;
        int jpf = (jn < NN) ? jn : (s * 64);
        na[0] = *(const int4*)(ap + jpf);
        na[1] = *(const int4*)(ap + jpf + 4);
        na[2] = *(const int4*)(ap + jpf + 32);
        na[3] = *(const int4*)(ap + jpf + 36);
        // current s2 window (L1/L2-resident, 16 KB/head)
        float4 sv0 = *(const float4*)(s2q + jb);
        float4 sv1 = *(const float4*)(s2q + jb + 4);
        float4 sv2 = *(const float4*)(s2q + jb + 32);
        float4 sv3 = *(const float4*)(s2q + jb + 36);
        // B fragments (L2-resident WhT)
        const short* bp = bbase + jb;
        s16x8 b00 = *(const s16x8*)(bp);
        s16x8 b01 = *(const s16x8*)(bp + 32);
        s16x8 b10 = *(const s16x8*)(bp + 16 * NN);
        s16x8 b11 = *(const s16x8*)(bp + 16 * NN + 32);
        s16x8 b20 = *(const s16x8*)(bp + 32 * NN);
        s16x8 b21 = *(const s16x8*)(bp + 32 * NN + 32);
        s16x8 b30 = *(const s16x8*)(bp + 48 * NN);
        s16x8 b31 = *(const s16x8*)(bp + 48 * NN + 32);
        // score phase -> A fragments in registers (covers the vmem latency above)
        s16x8 A0, A1;
        unsigned* A0u = reinterpret_cast<unsigned*>(&A0);
        unsigned* A1u = reinterpret_cast<unsigned*>(&A1);
        A0u[0] = mk(sv0.x, sv0.y, ca[0].x, ca[0].y);
        A0u[1] = mk(sv0.z, sv0.w, ca[0].z, ca[0].w);
        A0u[2] = mk(sv1.x, sv1.y, ca[1].x, ca[1].y);
        A0u[3] = mk(sv1.z, sv1.w, ca[1].z, ca[1].w);
        A1u[0] = mk(sv2.x, sv2.y, ca[2].x, ca[2].y);
        A1u[1] = mk(sv2.z, sv2.w, ca[2].z, ca[2].w);
        A1u[2] = mk(sv3.x, sv3.y, ca[3].x, ca[3].y);
        A1u[3] = mk(sv3.z, sv3.w, ca[3].z, ca[3].w);
        // PV + l-sum
        acc_l  = __builtin_amdgcn_mfma_f32_16x16x32_bf16(A0, ones, acc_l, 0, 0, 0);
        acc_l  = __builtin_amdgcn_mfma_f32_16x16x32_bf16(A1, ones, acc_l, 0, 0, 0);
        acc[0] = __builtin_amdgcn_mfma_f32_16x16x32_bf16(A0, b00, acc[0], 0, 0, 0);
        acc[0] = __builtin_amdgcn_mfma_f32_16x16x32_bf16(A1, b01, acc[0], 0, 0, 0);
        acc[1] = __builtin_amdgcn_mfma_f32_16x16x32_bf16(A0, b10, acc[1], 0, 0, 0);
        acc[1] = __builtin_amdgcn_mfma_f32_16x16x32_bf16(A1, b11, acc[1], 0, 0, 0);
        acc[2] = __builtin_amdgcn_mfma_f32_16x16x32_bf16(A0, b20, acc[2], 0, 0, 0);
        acc[2] = __builtin_amdgcn_mfma_f32_16x16x32_bf16(A1, b21, acc[2], 0, 0, 0);
        acc[3] = __builtin_amdgcn_mfma_f32_16x16x32_bf16(A0, b30, acc[3], 0, 0, 0);
        acc[3] = __builtin_amdgcn_mfma_f32_16x16x32_bf16(A1, b31, acc[3], 0, 0, 0);
    };

    // prologue: adj for iter 0
    int4 a0[4], a1[4];
    int jb = s * 64;
    a0[0] = *(const int4*)(ap + jb);
    a0[1] = *(const int4*)(ap + jb + 4);
    a0[2] = *(const int4*)(ap + jb + 32);
    a0[3] = *(const int4*)(ap + jb + 36);
    #pragma unroll 1
    for (int it = 0; it < NN / (NSPLIT * 64) / 2; ++it) {
        body(jb, a0, a1);
        body(jb + NSPLIT * 64, a1, a0);
        jb += 2 * NSPLIT * 64;
    }

    const int widx = ((ib * NSPLIT + s) * NH + h) * 16;
    // acc_l: all 16 cols hold the row sums; rows (lane>>4)*4+q
    if (row16 == 0) {
        #pragma unroll
        for (int q = 0; q < 4; ++q) ws_l[widx + (lane >> 4) * 4 + q] = acc_l[q];
    }
    float* apx = ws_acc + (size_t)widx * 64;
    #pragma unroll
    for (int c = 0; c < 4; ++c) {
        #pragma unroll
        for (int q = 0; q < 4; ++q) {
            int row = (lane >> 4) * 4 + q;
            int col = c * 16 + row16;
            apx[row * 64 + col] = acc[c][q];
        }
    }
}

// Kernel D: merge NSPLIT j-splits, divide by l, write out[n][h*64+o]
__global__ __launch_bounds__(256) void k_merge(
    const float* __restrict__ ws_acc, const float* __restrict__ ws_l,
    float* __restrict__ out)
{
    const int idx = blockIdx.x * 256 + threadIdx.x;
    const int o = idx & 63;
    const int h = (idx >> 6) & 3;
    const int n = idx >> 8;
    const int ib = n >> 4, r = n & 15;
    float l = 0.f, v = 0.f;
    #pragma unroll
    for (int s = 0; s < NSPLIT; ++s) {
        const int w = ((ib * NSPLIT + s) * NH + h) * 16 + r;
        l += ws_l[w];
        v += ws_acc[(size_t)w * 64 + o];
    }
    out[idx] = v / l;
}

extern "C" void kernel_launch(void* const* d_in, const int* in_sizes, int n_in,
                              void* d_out, int out_size, void* d_ws, size_t ws_size,
                              hipStream_t stream) {
    (void)in_sizes; (void)n_in; (void)out_size; (void)ws_size;
    const float* x  = (const float*)d_in[0];
    const int*  adj = (const int*)d_in[1];
    const float* W  = (const float*)d_in[2];
    const float* a  = (const float*)d_in[3];
    float* out = (float*)d_out;
    char* ws = (char*)d_ws;

    size_t off = 0;
    short* WhT   = (short*)(ws + off); off += (size_t)NH * FOUT * NN * 2;   // 2 MB
    float* s1    = (float*)(ws + off); off += (size_t)NH * NN * 4;          // 64 KB
    float* s2    = (float*)(ws + off); off += (size_t)NH * NN * 4;          // 64 KB
    float* c1g   = (float*)(ws + off); off += (size_t)NH * NN * 4;          // 64 KB
    float* c2g   = (float*)(ws + off); off += (size_t)NH * NN * 4;          // 64 KB
    float* ws_l  = (float*)(ws + off); off += (size_t)256 * NSPLIT * NH * 16 * 4;  // 256 KB
    float* ws_acc= (float*)(ws + off);                                      // 16.8 MB

    k_wh<<<dim3(64, 4), 256, 0, stream>>>(x, W, a, WhT, s1, s2);
    k_prep<<<NH * NN / 256, 256, 0, stream>>>(s1, s2, c1g, c2g);
    k_attn<<<dim3(256, NSPLIT), 256, 0, stream>>>(adj, WhT, c1g, c2g, s2, ws_acc, ws_l);
    k_merge<<<4096, 256, 0, stream>>>(ws_acc, ws_l, out);
}

// Round 8
// 118.108 us; speedup vs baseline: 1.0309x; 1.0309x over previous
//
#include <hip/hip_runtime.h>

#define NN 4096
#define FIN 256
#define FOUT 64
#define NH 4
#define NSPLIT 4

using f32x4 = __attribute__((ext_vector_type(4))) float;
using s16x8 = __attribute__((ext_vector_type(8))) short;
typedef unsigned long long u64;

__device__ __forceinline__ unsigned short f32_to_bf16_rne(float f) {
    unsigned b = __float_as_uint(f);
    b += 0x7FFFu + ((b >> 16) & 1u);
    return (unsigned short)(b >> 16);
}

// Kernel A: Wh[h] = x @ W[h] via bf16 MFMA -> WhT bf16 [H][FOUT][NN]; s1,s2 (pre-scaled log2e)
__global__ __launch_bounds__(256) void k_wh(
    const float* __restrict__ x, const float* __restrict__ W,
    const float* __restrict__ a, short* __restrict__ WhT,
    float* __restrict__ s1, float* __restrict__ s2)
{
    __shared__ unsigned short xs[64 * 256];   // bf16 x-tile, XOR-swizzled (16B granule), 32 KB
    __shared__ unsigned short wt[64 * 256];   // bf16 W^T [o][f], XOR-swizzled, 32 KB
    const int nb = blockIdx.x, h = blockIdx.y, t = threadIdx.x;
    const int n0 = nb * 64;
    {
        const float4* xg = reinterpret_cast<const float4*>(x + (size_t)n0 * FIN);
        for (int k = t; k < 64 * FIN / 4; k += 256) {
            float4 v = xg[k];
            int row = k >> 6, fq = k & 63;
            u64 pk = (u64)f32_to_bf16_rne(v.x) | ((u64)f32_to_bf16_rne(v.y) << 16)
                   | ((u64)f32_to_bf16_rne(v.z) << 32) | ((u64)f32_to_bf16_rne(v.w) << 48);
            int byte = (row * 512 + fq * 8) ^ ((row & 7) << 4);
            *(u64*)((char*)xs + byte) = pk;
        }
        const float* Wg = W + (size_t)h * FIN * FOUT;
        for (int k = t; k < FIN * FOUT; k += 256) {
            int f = k >> 6, o = k & 63;
            unsigned short wv = f32_to_bf16_rne(Wg[k]);
            int byte = (o * 512 + f * 2) ^ ((o & 7) << 4);
            *(unsigned short*)((char*)wt + byte) = wv;
        }
    }
    __syncthreads();
    const int lane = t & 63, wv_ = t >> 6;
    const int rowA = lane & 15;
    const int kq = (lane >> 4) * 8;
    const int i0 = wv_ * 16;
    f32x4 acc[4];
    #pragma unroll
    for (int c = 0; c < 4; ++c) acc[c] = (f32x4){0.f, 0.f, 0.f, 0.f};
    const int arow = i0 + rowA;
    #pragma unroll
    for (int kb = 0; kb < FIN; kb += 32) {
        int ab = (arow * 512 + (kb + kq) * 2) ^ ((arow & 7) << 4);
        s16x8 af = *(const s16x8*)((char*)xs + ab);
        #pragma unroll
        for (int c = 0; c < 4; ++c) {
            int col = c * 16 + rowA;
            int bb = (col * 512 + (kb + kq) * 2) ^ ((col & 7) << 4);
            s16x8 bf = *(const s16x8*)((char*)wt + bb);
            acc[c] = __builtin_amdgcn_mfma_f32_16x16x32_bf16(af, bf, acc[c], 0, 0, 0);
        }
    }
    const int q0 = (lane >> 4) * 4;
    const float L2E = 1.4426950408889634f;
    float v1acc[4] = {0.f, 0.f, 0.f, 0.f}, v2acc[4] = {0.f, 0.f, 0.f, 0.f};
    #pragma unroll
    for (int c = 0; c < 4; ++c) {
        int col = c * 16 + rowA;
        float a1v = a[h * (2 * FOUT) + col];
        float a2v = a[h * (2 * FOUT) + FOUT + col];
        short* wp = WhT + ((size_t)(h * FOUT + col)) * NN + n0 + i0 + q0;
        alignas(8) unsigned short tmp[4];
        #pragma unroll
        for (int q = 0; q < 4; ++q) {
            float v = acc[c][q];
            tmp[q] = f32_to_bf16_rne(v);
            v1acc[q] = fmaf(v, a1v, v1acc[q]);
            v2acc[q] = fmaf(v, a2v, v2acc[q]);
        }
        __builtin_memcpy(wp, tmp, 8);
    }
    #pragma unroll
    for (int q = 0; q < 4; ++q) {
        float v1 = v1acc[q] * L2E, v2 = v2acc[q] * L2E;
        #pragma unroll
        for (int d = 1; d < 16; d <<= 1) {
            v1 += __shfl_xor(v1, d, 64);
            v2 += __shfl_xor(v2, d, 64);
        }
        if (rowA == 0) {
            int n = n0 + i0 + q0 + q;
            s1[h * NN + n] = v1;
            s2[h * NN + n] = v2;
        }
    }
}

// Kernel A2: pack adj into bitmask, packed[jw*NN + i] bit j%64
__global__ __launch_bounds__(256) void k_pack(const int* __restrict__ adj,
                                              u64* __restrict__ packed)
{
    const int t = threadIdx.x;
    const int lane = t & 63;
    const int row = blockIdx.x * 4 + (t >> 6);
    const int* ap = adj + (size_t)row * NN + lane;
    u64* pp = packed + row;
    #pragma unroll 4
    for (int jw = 0; jw < 64; ++jw) {
        int av = ap[jw * 64];
        u64 m = __ballot(av != 0);
        if (lane == 0) pp[(size_t)jw * NN] = m;
    }
}

// Kernel B: per-row constants c1 = s1 - M, c2 = 0.2*s1 - M  (M = LeakyReLU(s1 + max_j s2))
__global__ __launch_bounds__(256) void k_prep(
    const float* __restrict__ s1, const float* __restrict__ s2,
    float* __restrict__ c1g, float* __restrict__ c2g)
{
    const int t = threadIdx.x;
    const int idx = blockIdx.x * 256 + t;      // over NH*NN
    const int h = idx >> 12;
    __shared__ float red[256];
    const float* s2p = s2 + (h << 12);
    float m = -1e30f;
    for (int j = t; j < NN; j += 256) m = fmaxf(m, s2p[j]);
    red[t] = m;
    __syncthreads();
    for (int st = 128; st > 0; st >>= 1) {
        if (t < st) red[t] = fmaxf(red[t], red[t + st]);
        __syncthreads();
    }
    float s2mv = red[0];
    float v = s1[idx];
    float tt = v + s2mv;
    float M = fmaxf(tt, 0.2f * tt);
    c1g[idx] = v - M;
    c2g[idx] = fmaf(0.2f, v, -M);
}

// Kernel C: fused masked-softmax + PV. Block = 4 waves on ONE head, 64 i-rows
// (wave w -> rows ib64*64 + w*16 ..+15). All 4 waves issue IDENTICAL B-frag and
// s2 addresses -> L1 broadcast, 4x less unique L2 traffic. P built entirely in
// registers in the A-fragment layout (lane 16g+r scores row r, j = jb+8g+q and
// jb+32+8g+q). Masks: one per-lane u64 vector load per iter from the bitmask.
// No LDS, no scalar-mem in the loop. Masks+s2 prefetched 1-deep.
__global__ __launch_bounds__(256, 4) void k_attn(
    const u64* __restrict__ packed, const short* __restrict__ WhT,
    const float* __restrict__ c1g, const float* __restrict__ c2g,
    const float* __restrict__ s2,
    float* __restrict__ ws_acc, float* __restrict__ ws_l)
{
    const int t = threadIdx.x;
    const int lane = t & 63;
    const int w = t >> 6;
    const int ib64 = blockIdx.x;
    const int h = blockIdx.y;
    const int s = blockIdx.z;
    const int row16 = lane & 15;
    const int kbase = (lane >> 4) * 8;
    const int irow = ib64 * 64 + w * 16 + row16;   // this lane's i-row

    const float c1v = c1g[h * NN + irow];
    const float c2v = c2g[h * NN + irow];

    f32x4 acc[4], acc_l;
    #pragma unroll
    for (int c = 0; c < 4; ++c) acc[c] = (f32x4){0.f, 0.f, 0.f, 0.f};
    acc_l = (f32x4){0.f, 0.f, 0.f, 0.f};
    s16x8 ones;
    #pragma unroll
    for (int i = 0; i < 8; ++i) ones[i] = (short)0x3F80;   // bf16 1.0

    const float* s2q = s2 + h * NN + kbase;                 // + jb + {0,4,32,36}
    const u64*   mb  = packed + irow;                       // + (jb>>6)*NN
    const short* bbase = WhT + (size_t)h * FOUT * NN + (size_t)row16 * NN + kbase;

    // one packed A-dword from 2 scores + 2 mask bits
    auto mk = [&](float sa, float sb, unsigned bits, int q0) -> unsigned {
        float e0 = fmaxf(c1v + sa, fmaf(0.2f, sa, c2v));
        float e1 = fmaxf(c1v + sb, fmaf(0.2f, sb, c2v));
        float p0 = __builtin_amdgcn_exp2f(e0);
        float p1 = __builtin_amdgcn_exp2f(e1);
        p0 = (bits & (1u << q0)) ? p0 : 0.f;
        p1 = (bits & (2u << q0)) ? p1 : 0.f;
        unsigned pk;
        asm("v_cvt_pk_bf16_f32 %0, %1, %2" : "=v"(pk) : "v"(p0), "v"(p1));
        return pk;
    };

    auto body = [&](int jb, u64 cm, f32x4 (&cs)[4], u64& nm, f32x4 (&ns)[4]) {
        // prefetch next iter's mask + s2 (1-deep)
        int jn = jb + NSPLIT * 64;
        int jpf = (jn < NN) ? jn : (s * 64);
        nm = mb[(size_t)(jpf >> 6) * NN];
        ns[0] = *(const f32x4*)(s2q + jpf);
        ns[1] = *(const f32x4*)(s2q + jpf + 4);
        ns[2] = *(const f32x4*)(s2q + jpf + 32);
        ns[3] = *(const f32x4*)(s2q + jpf + 36);
        // B fragments (shared across the block's 4 waves -> L1)
        const short* bp = bbase + jb;
        s16x8 b00 = *(const s16x8*)(bp);
        s16x8 b01 = *(const s16x8*)(bp + 32);
        s16x8 b10 = *(const s16x8*)(bp + 16 * NN);
        s16x8 b11 = *(const s16x8*)(bp + 16 * NN + 32);
        s16x8 b20 = *(const s16x8*)(bp + 32 * NN);
        s16x8 b21 = *(const s16x8*)(bp + 32 * NN + 32);
        s16x8 b30 = *(const s16x8*)(bp + 48 * NN);
        s16x8 b31 = *(const s16x8*)(bp + 48 * NN + 32);
        // per-lane 8-bit mask fields for this window
        unsigned ml8 = ((unsigned)cm >> kbase) & 0xFFu;
        unsigned mh8 = ((unsigned)(cm >> 32) >> kbase) & 0xFFu;
        // score phase -> A fragments in registers (covers B latency)
        s16x8 A0, A1;
        unsigned* A0u = reinterpret_cast<unsigned*>(&A0);
        unsigned* A1u = reinterpret_cast<unsigned*>(&A1);
        A0u[0] = mk(cs[0][0], cs[0][1], ml8, 0);
        A0u[1] = mk(cs[0][2], cs[0][3], ml8, 2);
        A0u[2] = mk(cs[1][0], cs[1][1], ml8, 4);
        A0u[3] = mk(cs[1][2], cs[1][3], ml8, 6);
        A1u[0] = mk(cs[2][0], cs[2][1], mh8, 0);
        A1u[1] = mk(cs[2][2], cs[2][3], mh8, 2);
        A1u[2] = mk(cs[3][0], cs[3][1], mh8, 4);
        A1u[3] = mk(cs[3][2], cs[3][3], mh8, 6);
        // PV + l-sum
        acc_l  = __builtin_amdgcn_mfma_f32_16x16x32_bf16(A0, ones, acc_l, 0, 0, 0);
        acc_l  = __builtin_amdgcn_mfma_f32_16x16x32_bf16(A1, ones, acc_l, 0, 0, 0);
        acc[0] = __builtin_amdgcn_mfma_f32_16x16x32_bf16(A0, b00, acc[0], 0, 0, 0);
        acc[0] = __builtin_amdgcn_mfma_f32_16x16x32_bf16(A1, b01, acc[0], 0, 0, 0);
        acc[1] = __builtin_amdgcn_mfma_f32_16x16x32_bf16(A0, b10, acc[1], 0, 0, 0);
        acc[1] = __builtin_amdgcn_mfma_f32_16x16x32_bf16(A1, b11, acc[1], 0, 0, 0);
        acc[2] = __builtin_amdgcn_mfma_f32_16x16x32_bf16(A0, b20, acc[2], 0, 0, 0);
        acc[2] = __builtin_amdgcn_mfma_f32_16x16x32_bf16(A1, b21, acc[2], 0, 0, 0);
        acc[3] = __builtin_amdgcn_mfma_f32_16x16x32_bf16(A0, b30, acc[3], 0, 0, 0);
        acc[3] = __builtin_amdgcn_mfma_f32_16x16x32_bf16(A1, b31, acc[3], 0, 0, 0);
    };

    // prologue: iter-0 mask + s2
    u64 m0, m1;
    f32x4 sv0[4], sv1[4];
    int jb = s * 64;
    {
        m0 = mb[(size_t)(jb >> 6) * NN];
        sv0[0] = *(const f32x4*)(s2q + jb);
        sv0[1] = *(const f32x4*)(s2q + jb + 4);
        sv0[2] = *(const f32x4*)(s2q + jb + 32);
        sv0[3] = *(const f32x4*)(s2q + jb + 36);
    }
    #pragma unroll 1
    for (int it = 0; it < NN / (NSPLIT * 64) / 2; ++it) {
        body(jb, m0, sv0, m1, sv1);
        body(jb + NSPLIT * 64, m1, sv1, m0, sv0);
        jb += 2 * NSPLIT * 64;
    }

    // widx uses the global 16-row block index so k_merge is unchanged
    const int ibg = ib64 * 4 + w;
    const int widx = ((ibg * NSPLIT + s) * NH + h) * 16;
    if (row16 == 0) {
        #pragma unroll
        for (int q = 0; q < 4; ++q) ws_l[widx + (lane >> 4) * 4 + q] = acc_l[q];
    }
    float* apx = ws_acc + (size_t)widx * 64;
    #pragma unroll
    for (int c = 0; c < 4; ++c) {
        #pragma unroll
        for (int q = 0; q < 4; ++q) {
            int row = (lane >> 4) * 4 + q;
            int col = c * 16 + row16;
            apx[row * 64 + col] = acc[c][q];
        }
    }
}

// Kernel D: merge NSPLIT j-splits, divide by l, write out[n][h*64+o]
__global__ __launch_bounds__(256) void k_merge(
    const float* __restrict__ ws_acc, const float* __restrict__ ws_l,
    float* __restrict__ out)
{
    const int idx = blockIdx.x * 256 + threadIdx.x;
    const int o = idx & 63;
    const int h = (idx >> 6) & 3;
    const int n = idx >> 8;
    const int ib = n >> 4, r = n & 15;
    float l = 0.f, v = 0.f;
    #pragma unroll
    for (int s = 0; s < NSPLIT; ++s) {
        const int w = ((ib * NSPLIT + s) * NH + h) * 16 + r;
        l += ws_l[w];
        v += ws_acc[(size_t)w * 64 + o];
    }
    out[idx] = v / l;
}

extern "C" void kernel_launch(void* const* d_in, const int* in_sizes, int n_in,
                              void* d_out, int out_size, void* d_ws, size_t ws_size,
                              hipStream_t stream) {
    (void)in_sizes; (void)n_in; (void)out_size; (void)ws_size;
    const float* x  = (const float*)d_in[0];
    const int*  adj = (const int*)d_in[1];
    const float* W  = (const float*)d_in[2];
    const float* a  = (const float*)d_in[3];
    float* out = (float*)d_out;
    char* ws = (char*)d_ws;

    size_t off = 0;
    short* WhT   = (short*)(ws + off); off += (size_t)NH * FOUT * NN * 2;   // 2 MB
    float* s1    = (float*)(ws + off); off += (size_t)NH * NN * 4;          // 64 KB
    float* s2    = (float*)(ws + off); off += (size_t)NH * NN * 4;          // 64 KB
    float* c1g   = (float*)(ws + off); off += (size_t)NH * NN * 4;          // 64 KB
    float* c2g   = (float*)(ws + off); off += (size_t)NH * NN * 4;          // 64 KB
    u64*   packed= (u64*)  (ws + off); off += (size_t)(NN / 64) * NN * 8;   // 2 MB
    float* ws_l  = (float*)(ws + off); off += (size_t)256 * NSPLIT * NH * 16 * 4;  // 256 KB
    float* ws_acc= (float*)(ws + off);                                      // 16.8 MB

    k_wh<<<dim3(64, 4), 256, 0, stream>>>(x, W, a, WhT, s1, s2);
    k_pack<<<1024, 256, 0, stream>>>(adj, packed);
    k_prep<<<NH * NN / 256, 256, 0, stream>>>(s1, s2, c1g, c2g);
    k_attn<<<dim3(64, NH, NSPLIT), 256, 0, stream>>>(packed, WhT, c1g, c2g, s2, ws_acc, ws_l);
    k_merge<<<4096, 256, 0, stream>>>(ws_acc, ws_l, out);
}

// Round 11
// 74.538 us; speedup vs baseline: 1.6336x; 1.5846x over previous
//
#include <hip/hip_runtime.h>

#define NN 4096
#define FIN 256
#define FOUT 64
#define NH 4
#define NSPLIT 4

using f32x4 = __attribute__((ext_vector_type(4))) float;
using s16x8 = __attribute__((ext_vector_type(8))) short;
typedef unsigned long long u64;

__device__ __forceinline__ unsigned short f32_to_bf16_rne(float f) {
    unsigned b = __float_as_uint(f);
    b += 0x7FFFu + ((b >> 16) & 1u);
    return (unsigned short)(b >> 16);
}

// Kernel A (R8-proven): Wh[h] = x @ W[h] via bf16 MFMA -> WhT bf16 [H][FOUT][NN]; s1,s2
__global__ __launch_bounds__(256) void k_wh(
    const float* __restrict__ x, const float* __restrict__ W,
    const float* __restrict__ a, short* __restrict__ WhT,
    float* __restrict__ s1, float* __restrict__ s2)
{
    __shared__ unsigned short xs[64 * 256];
    __shared__ unsigned short wt[64 * 256];
    const int nb = blockIdx.x, h = blockIdx.y, t = threadIdx.x;
    const int n0 = nb * 64;
    {
        const float4* xg = reinterpret_cast<const float4*>(x + (size_t)n0 * FIN);
        for (int k = t; k < 64 * FIN / 4; k += 256) {
            float4 v = xg[k];
            int row = k >> 6, fq = k & 63;
            u64 pk = (u64)f32_to_bf16_rne(v.x) | ((u64)f32_to_bf16_rne(v.y) << 16)
                   | ((u64)f32_to_bf16_rne(v.z) << 32) | ((u64)f32_to_bf16_rne(v.w) << 48);
            int byte = (row * 512 + fq * 8) ^ ((row & 7) << 4);
            *(u64*)((char*)xs + byte) = pk;
        }
        const float* Wg = W + (size_t)h * FIN * FOUT;
        for (int k = t; k < FIN * FOUT; k += 256) {
            int f = k >> 6, o = k & 63;
            unsigned short wv = f32_to_bf16_rne(Wg[k]);
            int byte = (o * 512 + f * 2) ^ ((o & 7) << 4);
            *(unsigned short*)((char*)wt + byte) = wv;
        }
    }
    __syncthreads();
    const int lane = t & 63, wv_ = t >> 6;
    const int rowA = lane & 15;
    const int kq = (lane >> 4) * 8;
    const int i0 = wv_ * 16;
    f32x4 acc[4];
    #pragma unroll
    for (int c = 0; c < 4; ++c) acc[c] = (f32x4){0.f, 0.f, 0.f, 0.f};
    const int arow = i0 + rowA;
    #pragma unroll
    for (int kb = 0; kb < FIN; kb += 32) {
        int ab = (arow * 512 + (kb + kq) * 2) ^ ((arow & 7) << 4);
        s16x8 af = *(const s16x8*)((char*)xs + ab);
        #pragma unroll
        for (int c = 0; c < 4; ++c) {
            int col = c * 16 + rowA;
            int bb = (col * 512 + (kb + kq) * 2) ^ ((col & 7) << 4);
            s16x8 bf = *(const s16x8*)((char*)wt + bb);
            acc[c] = __builtin_amdgcn_mfma_f32_16x16x32_bf16(af, bf, acc[c], 0, 0, 0);
        }
    }
    const int q0 = (lane >> 4) * 4;
    const float L2E = 1.4426950408889634f;
    float v1acc[4] = {0.f, 0.f, 0.f, 0.f}, v2acc[4] = {0.f, 0.f, 0.f, 0.f};
    #pragma unroll
    for (int c = 0; c < 4; ++c) {
        int col = c * 16 + rowA;
        float a1v = a[h * (2 * FOUT) + col];
        float a2v = a[h * (2 * FOUT) + FOUT + col];
        short* wp = WhT + ((size_t)(h * FOUT + col)) * NN + n0 + i0 + q0;
        alignas(8) unsigned short tmp[4];
        #pragma unroll
        for (int q = 0; q < 4; ++q) {
            float v = acc[c][q];
            tmp[q] = f32_to_bf16_rne(v);
            v1acc[q] = fmaf(v, a1v, v1acc[q]);
            v2acc[q] = fmaf(v, a2v, v2acc[q]);
        }
        __builtin_memcpy(wp, tmp, 8);
    }
    #pragma unroll
    for (int q = 0; q < 4; ++q) {
        float v1 = v1acc[q] * L2E, v2 = v2acc[q] * L2E;
        #pragma unroll
        for (int d = 1; d < 16; d <<= 1) {
            v1 += __shfl_xor(v1, d, 64);
            v2 += __shfl_xor(v2, d, 64);
        }
        if (rowA == 0) {
            int n = n0 + i0 + q0 + q;
            s1[h * NN + n] = v1;
            s2[h * NN + n] = v2;
        }
    }
}

// Kernel A2: pack adj into bitmask, packed[jw*NN + i] bit j%64
__global__ __launch_bounds__(256) void k_pack(const int* __restrict__ adj,
                                              u64* __restrict__ packed)
{
    const int t = threadIdx.x;
    const int lane = t & 63;
    const int row = blockIdx.x * 4 + (t >> 6);
    const int* ap = adj + (size_t)row * NN + lane;
    u64* pp = packed + row;
    #pragma unroll 4
    for (int jw = 0; jw < 64; ++jw) {
        int av = ap[jw * 64];
        u64 m = __ballot(av != 0);
        if (lane == 0) pp[(size_t)jw * NN] = m;
    }
}

// Kernel B: per-row constants c1 = s1 - M, c2 = 0.2*s1 - M
__global__ __launch_bounds__(256) void k_prep(
    const float* __restrict__ s1, const float* __restrict__ s2,
    float* __restrict__ c1g, float* __restrict__ c2g)
{
    const int t = threadIdx.x;
    const int idx = blockIdx.x * 256 + t;
    const int h = idx >> 12;
    __shared__ float red[256];
    const float* s2p = s2 + (h << 12);
    float m = -1e30f;
    for (int j = t; j < NN; j += 256) m = fmaxf(m, s2p[j]);
    red[t] = m;
    __syncthreads();
    for (int st = 128; st > 0; st >>= 1) {
        if (t < st) red[t] = fmaxf(red[t], red[t + st]);
        __syncthreads();
    }
    float s2mv = red[0];
    float v = s1[idx];
    float tt = v + s2mv;
    float M = fmaxf(tt, 0.2f * tt);
    c1g[idx] = v - M;
    c2g[idx] = fmaf(0.2f, v, -M);
}

// Kernel C: R8 compute + LDS-staged B tile. Per iter the block cooperatively
// stages the 8KB Wh j-block [o=64][jl=64] (2x16B per thread, coalesced) into a
// double-buffered XOR-swizzled LDS tile (k_wh's proven swizzle). Frag ds_reads
// fetch exactly the same (o,j) data R8's scattered global loads did.
// Body order (T14): stage-loads -> mask/s2 prefetch -> score phase (covers
// latency) -> ds_write -> ds_read frags -> MFMA; one barrier per iter.
__global__ __launch_bounds__(256, 4) void k_attn(
    const u64* __restrict__ packed, const short* __restrict__ WhT,
    const float* __restrict__ c1g, const float* __restrict__ c2g,
    const float* __restrict__ s2,
    float* __restrict__ ws_acc, float* __restrict__ ws_l)
{
    __shared__ unsigned short btile[2][64 * 64];   // 2 x 8KB, swizzled [o][jl]
    const int t = threadIdx.x;
    const int lane = t & 63;
    const int w = t >> 6;
    const int ib64 = blockIdx.x;
    const int h = blockIdx.y;
    const int s = blockIdx.z;
    const int row16 = lane & 15;
    const int kbase = (lane >> 4) * 8;
    const int irow = ib64 * 64 + w * 16 + row16;

    const float c1v = c1g[h * NN + irow];
    const float c2v = c2g[h * NN + irow];

    f32x4 acc[4], acc_l;
    #pragma unroll
    for (int c = 0; c < 4; ++c) acc[c] = (f32x4){0.f, 0.f, 0.f, 0.f};
    acc_l = (f32x4){0.f, 0.f, 0.f, 0.f};
    s16x8 ones;
    #pragma unroll
    for (int i = 0; i < 8; ++i) ones[i] = (short)0x3F80;   // bf16 1.0

    const float* s2q = s2 + h * NN + kbase;
    const u64*   mb  = packed + irow;

    // staging assignment: thread t covers rows so and so+32 at granule sj
    const int so = t >> 3;           // 0..31
    const int sj = (t & 7) * 8;      // j-offset within tile, 8 shorts = 16B
    const short* wsrc = WhT + (size_t)h * FOUT * NN;
    const int wb0 = (so * 128 + sj * 2) ^ ((so & 7) << 4);          // LDS write bytes
    const int wb1 = ((so + 32) * 128 + sj * 2) ^ ((so & 7) << 4);   // (so+32)&7 == so&7

    // frag read byte offsets (k_wh's swizzle formula)
    int rd[4][2];
    #pragma unroll
    for (int c = 0; c < 4; ++c) {
        int o = c * 16 + row16;
        #pragma unroll
        for (int hf = 0; hf < 2; ++hf)
            rd[c][hf] = (o * 128 + (hf * 32 + kbase) * 2) ^ ((o & 7) << 4);
    }

    auto mk = [&](float sa, float sb, unsigned bits, int q0) -> unsigned {
        float e0 = fmaxf(c1v + sa, fmaf(0.2f, sa, c2v));
        float e1 = fmaxf(c1v + sb, fmaf(0.2f, sb, c2v));
        float p0 = __builtin_amdgcn_exp2f(e0);
        float p1 = __builtin_amdgcn_exp2f(e1);
        p0 = (bits & (1u << q0)) ? p0 : 0.f;
        p1 = (bits & (2u << q0)) ? p1 : 0.f;
        unsigned pk;
        asm("v_cvt_pk_bf16_f32 %0, %1, %2" : "=v"(pk) : "v"(p0), "v"(p1));
        return pk;
    };

    auto body = [&](int jb, char* btr, char* btw, u64 cm, f32x4 (&cs)[4],
                    u64& nm, f32x4 (&ns)[4]) {
        int jn = jb + NSPLIT * 64;
        int jpf = (jn < NN) ? jn : (s * 64);
        // (1) stage global loads for NEXT j-block (consumed after score phase)
        s16x8 st0 = *(const s16x8*)(wsrc + (size_t)so * NN + jpf + sj);
        s16x8 st1 = *(const s16x8*)(wsrc + (size_t)(so + 32) * NN + jpf + sj);
        // (2) next iter's mask + s2
        nm = mb[(size_t)(jpf >> 6) * NN];
        ns[0] = *(const f32x4*)(s2q + jpf);
        ns[1] = *(const f32x4*)(s2q + jpf + 4);
        ns[2] = *(const f32x4*)(s2q + jpf + 32);
        ns[3] = *(const f32x4*)(s2q + jpf + 36);
        // (3) score phase -> A fragments (covers the latency of (1)/(2))
        unsigned ml8 = ((unsigned)cm >> kbase) & 0xFFu;
        unsigned mh8 = ((unsigned)(cm >> 32) >> kbase) & 0xFFu;
        s16x8 A0, A1;
        unsigned* A0u = reinterpret_cast<unsigned*>(&A0);
        unsigned* A1u = reinterpret_cast<unsigned*>(&A1);
        A0u[0] = mk(cs[0][0], cs[0][1], ml8, 0);
        A0u[1] = mk(cs[0][2], cs[0][3], ml8, 2);
        A0u[2] = mk(cs[1][0], cs[1][1], ml8, 4);
        A0u[3] = mk(cs[1][2], cs[1][3], ml8, 6);
        A1u[0] = mk(cs[2][0], cs[2][1], mh8, 0);
        A1u[1] = mk(cs[2][2], cs[2][3], mh8, 2);
        A1u[2] = mk(cs[3][0], cs[3][1], mh8, 4);
        A1u[3] = mk(cs[3][2], cs[3][3], mh8, 6);
        // (4) commit staged tile for next iter
        *(s16x8*)(btw + wb0) = st0;
        *(s16x8*)(btw + wb1) = st1;
        // (5) B frags from current tile (2-way bank aliasing only) + MFMAs
        s16x8 b00 = *(const s16x8*)(btr + rd[0][0]);
        s16x8 b01 = *(const s16x8*)(btr + rd[0][1]);
        s16x8 b10 = *(const s16x8*)(btr + rd[1][0]);
        s16x8 b11 = *(const s16x8*)(btr + rd[1][1]);
        s16x8 b20 = *(const s16x8*)(btr + rd[2][0]);
        s16x8 b21 = *(const s16x8*)(btr + rd[2][1]);
        s16x8 b30 = *(const s16x8*)(btr + rd[3][0]);
        s16x8 b31 = *(const s16x8*)(btr + rd[3][1]);
        acc_l  = __builtin_amdgcn_mfma_f32_16x16x32_bf16(A0, ones, acc_l, 0, 0, 0);
        acc_l  = __builtin_amdgcn_mfma_f32_16x16x32_bf16(A1, ones, acc_l, 0, 0, 0);
        acc[0] = __builtin_amdgcn_mfma_f32_16x16x32_bf16(A0, b00, acc[0], 0, 0, 0);
        acc[0] = __builtin_amdgcn_mfma_f32_16x16x32_bf16(A1, b01, acc[0], 0, 0, 0);
        acc[1] = __builtin_amdgcn_mfma_f32_16x16x32_bf16(A0, b10, acc[1], 0, 0, 0);
        acc[1] = __builtin_amdgcn_mfma_f32_16x16x32_bf16(A1, b11, acc[1], 0, 0, 0);
        acc[2] = __builtin_amdgcn_mfma_f32_16x16x32_bf16(A0, b20, acc[2], 0, 0, 0);
        acc[2] = __builtin_amdgcn_mfma_f32_16x16x32_bf16(A1, b21, acc[2], 0, 0, 0);
        acc[3] = __builtin_amdgcn_mfma_f32_16x16x32_bf16(A0, b30, acc[3], 0, 0, 0);
        acc[3] = __builtin_amdgcn_mfma_f32_16x16x32_bf16(A1, b31, acc[3], 0, 0, 0);
    };

    // prologue: stage iter-0 tile into btile[0]; load iter-0 mask + s2
    u64 m0, m1;
    f32x4 sv0[4], sv1[4];
    int jb = s * 64;
    {
        s16x8 st0 = *(const s16x8*)(wsrc + (size_t)so * NN + jb + sj);
        s16x8 st1 = *(const s16x8*)(wsrc + (size_t)(so + 32) * NN + jb + sj);
        *(s16x8*)((char*)&btile[0][0] + wb0) = st0;
        *(s16x8*)((char*)&btile[0][0] + wb1) = st1;
        m0 = mb[(size_t)(jb >> 6) * NN];
        sv0[0] = *(const f32x4*)(s2q + jb);
        sv0[1] = *(const f32x4*)(s2q + jb + 4);
        sv0[2] = *(const f32x4*)(s2q + jb + 32);
        sv0[3] = *(const f32x4*)(s2q + jb + 36);
    }
    __syncthreads();
    #pragma unroll 1
    for (int it = 0; it < NN / (NSPLIT * 64) / 2; ++it) {
        body(jb, (char*)&btile[0][0], (char*)&btile[1][0], m0, sv0, m1, sv1);
        __syncthreads();
        body(jb + NSPLIT * 64, (char*)&btile[1][0], (char*)&btile[0][0], m1, sv1, m0, sv0);
        __syncthreads();
        jb += 2 * NSPLIT * 64;
    }

    const int ibg = ib64 * 4 + w;
    const int widx = ((ibg * NSPLIT + s) * NH + h) * 16;
    if (row16 == 0) {
        #pragma unroll
        for (int q = 0; q < 4; ++q) ws_l[widx + (lane >> 4) * 4 + q] = acc_l[q];
    }
    float* apx = ws_acc + (size_t)widx * 64;
    #pragma unroll
    for (int c = 0; c < 4; ++c) {
        #pragma unroll
        for (int q = 0; q < 4; ++q) {
            int row = (lane >> 4) * 4 + q;
            int col = c * 16 + row16;
            apx[row * 64 + col] = acc[c][q];
        }
    }
}

// Kernel D: merge NSPLIT j-splits, divide by l, write out[n][h*64+o]
__global__ __launch_bounds__(256) void k_merge(
    const float* __restrict__ ws_acc, const float* __restrict__ ws_l,
    float* __restrict__ out)
{
    const int idx = blockIdx.x * 256 + threadIdx.x;
    const int o = idx & 63;
    const int h = (idx >> 6) & 3;
    const int n = idx >> 8;
    const int ib = n >> 4, r = n & 15;
    float l = 0.f, v = 0.f;
    #pragma unroll
    for (int s = 0; s < NSPLIT; ++s) {
        const int w = ((ib * NSPLIT + s) * NH + h) * 16 + r;
        l += ws_l[w];
        v += ws_acc[(size_t)w * 64 + o];
    }
    out[idx] = v / l;
}

extern "C" void kernel_launch(void* const* d_in, const int* in_sizes, int n_in,
                              void* d_out, int out_size, void* d_ws, size_t ws_size,
                              hipStream_t stream) {
    (void)in_sizes; (void)n_in; (void)out_size; (void)ws_size;
    const float* x  = (const float*)d_in[0];
    const int*  adj = (const int*)d_in[1];
    const float* W  = (const float*)d_in[2];
    const float* a  = (const float*)d_in[3];
    float* out = (float*)d_out;
    char* ws = (char*)d_ws;

    size_t off = 0;
    short* WhT   = (short*)(ws + off); off += (size_t)NH * FOUT * NN * 2;   // 2 MB
    float* s1    = (float*)(ws + off); off += (size_t)NH * NN * 4;          // 64 KB
    float* s2    = (float*)(ws + off); off += (size_t)NH * NN * 4;          // 64 KB
    float* c1g   = (float*)(ws + off); off += (size_t)NH * NN * 4;          // 64 KB
    float* c2g   = (float*)(ws + off); off += (size_t)NH * NN * 4;          // 64 KB
    u64*   packed= (u64*)  (ws + off); off += (size_t)(NN / 64) * NN * 8;   // 2 MB
    float* ws_l  = (float*)(ws + off); off += (size_t)256 * NSPLIT * NH * 16 * 4;  // 256 KB
    float* ws_acc= (float*)(ws + off);                                      // 16.8 MB

    k_wh<<<dim3(64, 4), 256, 0, stream>>>(x, W, a, WhT, s1, s2);
    k_pack<<<1024, 256, 0, stream>>>(adj, packed);
    k_prep<<<NH * NN / 256, 256, 0, stream>>>(s1, s2, c1g, c2g);
    k_attn<<<dim3(64, NH, NSPLIT), 256, 0, stream>>>(packed, WhT, c1g, c2g, s2, ws_acc, ws_l);
    k_merge<<<4096, 256, 0, stream>>>(ws_acc, ws_l, out);
}

// Round 12
// 67.741 us; speedup vs baseline: 1.7975x; 1.1003x over previous
//
#include <hip/hip_runtime.h>

#define NN 4096
#define FIN 256
#define FOUT 64
#define NH 4
#define NSPLIT 4

using f32x4 = __attribute__((ext_vector_type(4))) float;
using s16x8 = __attribute__((ext_vector_type(8))) short;
typedef unsigned long long u64;

__device__ __forceinline__ unsigned short f32_to_bf16_rne(float f) {
    unsigned b = __float_as_uint(f);
    b += 0x7FFFu + ((b >> 16) & 1u);
    return (unsigned short)(b >> 16);
}

// Kernel A (R8-proven): Wh[h] = x @ W[h] via bf16 MFMA -> WhT bf16 [H][FOUT][NN]; s1,s2
__global__ __launch_bounds__(256) void k_wh(
    const float* __restrict__ x, const float* __restrict__ W,
    const float* __restrict__ a, short* __restrict__ WhT,
    float* __restrict__ s1, float* __restrict__ s2)
{
    __shared__ unsigned short xs[64 * 256];
    __shared__ unsigned short wt[64 * 256];
    const int nb = blockIdx.x, h = blockIdx.y, t = threadIdx.x;
    const int n0 = nb * 64;
    {
        const float4* xg = reinterpret_cast<const float4*>(x + (size_t)n0 * FIN);
        for (int k = t; k < 64 * FIN / 4; k += 256) {
            float4 v = xg[k];
            int row = k >> 6, fq = k & 63;
            u64 pk = (u64)f32_to_bf16_rne(v.x) | ((u64)f32_to_bf16_rne(v.y) << 16)
                   | ((u64)f32_to_bf16_rne(v.z) << 32) | ((u64)f32_to_bf16_rne(v.w) << 48);
            int byte = (row * 512 + fq * 8) ^ ((row & 7) << 4);
            *(u64*)((char*)xs + byte) = pk;
        }
        const float* Wg = W + (size_t)h * FIN * FOUT;
        for (int k = t; k < FIN * FOUT; k += 256) {
            int f = k >> 6, o = k & 63;
            unsigned short wv = f32_to_bf16_rne(Wg[k]);
            int byte = (o * 512 + f * 2) ^ ((o & 7) << 4);
            *(unsigned short*)((char*)wt + byte) = wv;
        }
    }
    __syncthreads();
    const int lane = t & 63, wv_ = t >> 6;
    const int rowA = lane & 15;
    const int kq = (lane >> 4) * 8;
    const int i0 = wv_ * 16;
    f32x4 acc[4];
    #pragma unroll
    for (int c = 0; c < 4; ++c) acc[c] = (f32x4){0.f, 0.f, 0.f, 0.f};
    const int arow = i0 + rowA;
    #pragma unroll
    for (int kb = 0; kb < FIN; kb += 32) {
        int ab = (arow * 512 + (kb + kq) * 2) ^ ((arow & 7) << 4);
        s16x8 af = *(const s16x8*)((char*)xs + ab);
        #pragma unroll
        for (int c = 0; c < 4; ++c) {
            int col = c * 16 + rowA;
            int bb = (col * 512 + (kb + kq) * 2) ^ ((col & 7) << 4);
            s16x8 bf = *(const s16x8*)((char*)wt + bb);
            acc[c] = __builtin_amdgcn_mfma_f32_16x16x32_bf16(af, bf, acc[c], 0, 0, 0);
        }
    }
    const int q0 = (lane >> 4) * 4;
    const float L2E = 1.4426950408889634f;
    float v1acc[4] = {0.f, 0.f, 0.f, 0.f}, v2acc[4] = {0.f, 0.f, 0.f, 0.f};
    #pragma unroll
    for (int c = 0; c < 4; ++c) {
        int col = c * 16 + rowA;
        float a1v = a[h * (2 * FOUT) + col];
        float a2v = a[h * (2 * FOUT) + FOUT + col];
        short* wp = WhT + ((size_t)(h * FOUT + col)) * NN + n0 + i0 + q0;
        alignas(8) unsigned short tmp[4];
        #pragma unroll
        for (int q = 0; q < 4; ++q) {
            float v = acc[c][q];
            tmp[q] = f32_to_bf16_rne(v);
            v1acc[q] = fmaf(v, a1v, v1acc[q]);
            v2acc[q] = fmaf(v, a2v, v2acc[q]);
        }
        __builtin_memcpy(wp, tmp, 8);
    }
    #pragma unroll
    for (int q = 0; q < 4; ++q) {
        float v1 = v1acc[q] * L2E, v2 = v2acc[q] * L2E;
        #pragma unroll
        for (int d = 1; d < 16; d <<= 1) {
            v1 += __shfl_xor(v1, d, 64);
            v2 += __shfl_xor(v2, d, 64);
        }
        if (rowA == 0) {
            int n = n0 + i0 + q0 + q;
            s1[h * NN + n] = v1;
            s2[h * NN + n] = v2;
        }
    }
}

// Kernel A2 (R12): pack adj into bitmask, packed[jw*NN + i] bit j%64.
// Wave = (row, 1024-j chunk). Lane l: 4 independent int4 loads (16 consecutive
// ints at j = jc*1024 + l*16) -> 16 local bits -> shift to (l&3)*16 -> 2-level
// shfl_xor OR-assemble -> lanes (l&3)==0 store the 16 u64 words. Deep ILP,
// 1 KB/load-instruction (the old ballot version was 256B + chained: 0.8 TB/s).
__global__ __launch_bounds__(256) void k_pack(const int* __restrict__ adj,
                                              u64* __restrict__ packed)
{
    const int t = threadIdx.x;
    const int lane = t & 63;
    const int idx = blockIdx.x * 4 + (t >> 6);   // (row, chunk)
    const int row = idx >> 2;
    const int jc  = idx & 3;
    const int* ap = adj + (size_t)row * NN + jc * 1024 + lane * 16;
    int4 a0 = *(const int4*)(ap);
    int4 a1 = *(const int4*)(ap + 4);
    int4 a2 = *(const int4*)(ap + 8);
    int4 a3 = *(const int4*)(ap + 12);
    unsigned b = 0;
    b |= (a0.x != 0) ? 0x0001u : 0u;  b |= (a0.y != 0) ? 0x0002u : 0u;
    b |= (a0.z != 0) ? 0x0004u : 0u;  b |= (a0.w != 0) ? 0x0008u : 0u;
    b |= (a1.x != 0) ? 0x0010u : 0u;  b |= (a1.y != 0) ? 0x0020u : 0u;
    b |= (a1.z != 0) ? 0x0040u : 0u;  b |= (a1.w != 0) ? 0x0080u : 0u;
    b |= (a2.x != 0) ? 0x0100u : 0u;  b |= (a2.y != 0) ? 0x0200u : 0u;
    b |= (a2.z != 0) ? 0x0400u : 0u;  b |= (a2.w != 0) ? 0x0800u : 0u;
    b |= (a3.x != 0) ? 0x1000u : 0u;  b |= (a3.y != 0) ? 0x2000u : 0u;
    b |= (a3.z != 0) ? 0x4000u : 0u;  b |= (a3.w != 0) ? 0x8000u : 0u;
    u64 word = (u64)b << ((lane & 3) * 16);
    word |= __shfl_xor(word, 1, 64);
    word |= __shfl_xor(word, 2, 64);
    if ((lane & 3) == 0) {
        int w = jc * 16 + (lane >> 2);
        packed[(size_t)w * NN + row] = word;
    }
}

// Kernel B: per-row constants c1 = s1 - M, c2 = 0.2*s1 - M
__global__ __launch_bounds__(256) void k_prep(
    const float* __restrict__ s1, const float* __restrict__ s2,
    float* __restrict__ c1g, float* __restrict__ c2g)
{
    const int t = threadIdx.x;
    const int idx = blockIdx.x * 256 + t;
    const int h = idx >> 12;
    __shared__ float red[256];
    const float* s2p = s2 + (h << 12);
    float m = -1e30f;
    for (int j = t; j < NN; j += 256) m = fmaxf(m, s2p[j]);
    red[t] = m;
    __syncthreads();
    for (int st = 128; st > 0; st >>= 1) {
        if (t < st) red[t] = fmaxf(red[t], red[t + st]);
        __syncthreads();
    }
    float s2mv = red[0];
    float v = s1[idx];
    float tt = v + s2mv;
    float M = fmaxf(tt, 0.2f * tt);
    c1g[idx] = v - M;
    c2g[idx] = fmaf(0.2f, v, -M);
}

// Kernel C (R11-proven): fused masked-softmax + PV with LDS-staged B tile.
__global__ __launch_bounds__(256, 4) void k_attn(
    const u64* __restrict__ packed, const short* __restrict__ WhT,
    const float* __restrict__ c1g, const float* __restrict__ c2g,
    const float* __restrict__ s2,
    float* __restrict__ ws_acc, float* __restrict__ ws_l)
{
    __shared__ unsigned short btile[2][64 * 64];   // 2 x 8KB, swizzled [o][jl]
    const int t = threadIdx.x;
    const int lane = t & 63;
    const int w = t >> 6;
    const int ib64 = blockIdx.x;
    const int h = blockIdx.y;
    const int s = blockIdx.z;
    const int row16 = lane & 15;
    const int kbase = (lane >> 4) * 8;
    const int irow = ib64 * 64 + w * 16 + row16;

    const float c1v = c1g[h * NN + irow];
    const float c2v = c2g[h * NN + irow];

    f32x4 acc[4], acc_l;
    #pragma unroll
    for (int c = 0; c < 4; ++c) acc[c] = (f32x4){0.f, 0.f, 0.f, 0.f};
    acc_l = (f32x4){0.f, 0.f, 0.f, 0.f};
    s16x8 ones;
    #pragma unroll
    for (int i = 0; i < 8; ++i) ones[i] = (short)0x3F80;   // bf16 1.0

    const float* s2q = s2 + h * NN + kbase;
    const u64*   mb  = packed + irow;

    const int so = t >> 3;
    const int sj = (t & 7) * 8;
    const short* wsrc = WhT + (size_t)h * FOUT * NN;
    const int wb0 = (so * 128 + sj * 2) ^ ((so & 7) << 4);
    const int wb1 = ((so + 32) * 128 + sj * 2) ^ ((so & 7) << 4);

    int rd[4][2];
    #pragma unroll
    for (int c = 0; c < 4; ++c) {
        int o = c * 16 + row16;
        #pragma unroll
        for (int hf = 0; hf < 2; ++hf)
            rd[c][hf] = (o * 128 + (hf * 32 + kbase) * 2) ^ ((o & 7) << 4);
    }

    auto mk = [&](float sa, float sb, unsigned bits, int q0) -> unsigned {
        float e0 = fmaxf(c1v + sa, fmaf(0.2f, sa, c2v));
        float e1 = fmaxf(c1v + sb, fmaf(0.2f, sb, c2v));
        float p0 = __builtin_amdgcn_exp2f(e0);
        float p1 = __builtin_amdgcn_exp2f(e1);
        p0 = (bits & (1u << q0)) ? p0 : 0.f;
        p1 = (bits & (2u << q0)) ? p1 : 0.f;
        unsigned pk;
        asm("v_cvt_pk_bf16_f32 %0, %1, %2" : "=v"(pk) : "v"(p0), "v"(p1));
        return pk;
    };

    auto body = [&](int jb, char* btr, char* btw, u64 cm, f32x4 (&cs)[4],
                    u64& nm, f32x4 (&ns)[4]) {
        int jn = jb + NSPLIT * 64;
        int jpf = (jn < NN) ? jn : (s * 64);
        // (1) stage global loads for NEXT j-block
        s16x8 st0 = *(const s16x8*)(wsrc + (size_t)so * NN + jpf + sj);
        s16x8 st1 = *(const s16x8*)(wsrc + (size_t)(so + 32) * NN + jpf + sj);
        // (2) next iter's mask + s2
        nm = mb[(size_t)(jpf >> 6) * NN];
        ns[0] = *(const f32x4*)(s2q + jpf);
        ns[1] = *(const f32x4*)(s2q + jpf + 4);
        ns[2] = *(const f32x4*)(s2q + jpf + 32);
        ns[3] = *(const f32x4*)(s2q + jpf + 36);
        // (3) score phase -> A fragments
        unsigned ml8 = ((unsigned)cm >> kbase) & 0xFFu;
        unsigned mh8 = ((unsigned)(cm >> 32) >> kbase) & 0xFFu;
        s16x8 A0, A1;
        unsigned* A0u = reinterpret_cast<unsigned*>(&A0);
        unsigned* A1u = reinterpret_cast<unsigned*>(&A1);
        A0u[0] = mk(cs[0][0], cs[0][1], ml8, 0);
        A0u[1] = mk(cs[0][2], cs[0][3], ml8, 2);
        A0u[2] = mk(cs[1][0], cs[1][1], ml8, 4);
        A0u[3] = mk(cs[1][2], cs[1][3], ml8, 6);
        A1u[0] = mk(cs[2][0], cs[2][1], mh8, 0);
        A1u[1] = mk(cs[2][2], cs[2][3], mh8, 2);
        A1u[2] = mk(cs[3][0], cs[3][1], mh8, 4);
        A1u[3] = mk(cs[3][2], cs[3][3], mh8, 6);
        // (4) commit staged tile for next iter
        *(s16x8*)(btw + wb0) = st0;
        *(s16x8*)(btw + wb1) = st1;
        // (5) B frags from current tile + MFMAs
        s16x8 b00 = *(const s16x8*)(btr + rd[0][0]);
        s16x8 b01 = *(const s16x8*)(btr + rd[0][1]);
        s16x8 b10 = *(const s16x8*)(btr + rd[1][0]);
        s16x8 b11 = *(const s16x8*)(btr + rd[1][1]);
        s16x8 b20 = *(const s16x8*)(btr + rd[2][0]);
        s16x8 b21 = *(const s16x8*)(btr + rd[2][1]);
        s16x8 b30 = *(const s16x8*)(btr + rd[3][0]);
        s16x8 b31 = *(const s16x8*)(btr + rd[3][1]);
        acc_l  = __builtin_amdgcn_mfma_f32_16x16x32_bf16(A0, ones, acc_l, 0, 0, 0);
        acc_l  = __builtin_amdgcn_mfma_f32_16x16x32_bf16(A1, ones, acc_l, 0, 0, 0);
        acc[0] = __builtin_amdgcn_mfma_f32_16x16x32_bf16(A0, b00, acc[0], 0, 0, 0);
        acc[0] = __builtin_amdgcn_mfma_f32_16x16x32_bf16(A1, b01, acc[0], 0, 0, 0);
        acc[1] = __builtin_amdgcn_mfma_f32_16x16x32_bf16(A0, b10, acc[1], 0, 0, 0);
        acc[1] = __builtin_amdgcn_mfma_f32_16x16x32_bf16(A1, b11, acc[1], 0, 0, 0);
        acc[2] = __builtin_amdgcn_mfma_f32_16x16x32_bf16(A0, b20, acc[2], 0, 0, 0);
        acc[2] = __builtin_amdgcn_mfma_f32_16x16x32_bf16(A1, b21, acc[2], 0, 0, 0);
        acc[3] = __builtin_amdgcn_mfma_f32_16x16x32_bf16(A0, b30, acc[3], 0, 0, 0);
        acc[3] = __builtin_amdgcn_mfma_f32_16x16x32_bf16(A1, b31, acc[3], 0, 0, 0);
    };

    u64 m0, m1;
    f32x4 sv0[4], sv1[4];
    int jb = s * 64;
    {
        s16x8 st0 = *(const s16x8*)(wsrc + (size_t)so * NN + jb + sj);
        s16x8 st1 = *(const s16x8*)(wsrc + (size_t)(so + 32) * NN + jb + sj);
        *(s16x8*)((char*)&btile[0][0] + wb0) = st0;
        *(s16x8*)((char*)&btile[0][0] + wb1) = st1;
        m0 = mb[(size_t)(jb >> 6) * NN];
        sv0[0] = *(const f32x4*)(s2q + jb);
        sv0[1] = *(const f32x4*)(s2q + jb + 4);
        sv0[2] = *(const f32x4*)(s2q + jb + 32);
        sv0[3] = *(const f32x4*)(s2q + jb + 36);
    }
    __syncthreads();
    #pragma unroll 1
    for (int it = 0; it < NN / (NSPLIT * 64) / 2; ++it) {
        body(jb, (char*)&btile[0][0], (char*)&btile[1][0], m0, sv0, m1, sv1);
        __syncthreads();
        body(jb + NSPLIT * 64, (char*)&btile[1][0], (char*)&btile[0][0], m1, sv1, m0, sv0);
        __syncthreads();
        jb += 2 * NSPLIT * 64;
    }

    const int ibg = ib64 * 4 + w;
    const int widx = ((ibg * NSPLIT + s) * NH + h) * 16;
    if (row16 == 0) {
        #pragma unroll
        for (int q = 0; q < 4; ++q) ws_l[widx + (lane >> 4) * 4 + q] = acc_l[q];
    }
    float* apx = ws_acc + (size_t)widx * 64;
    #pragma unroll
    for (int c = 0; c < 4; ++c) {
        #pragma unroll
        for (int q = 0; q < 4; ++q) {
            int row = (lane >> 4) * 4 + q;
            int col = c * 16 + row16;
            apx[row * 64 + col] = acc[c][q];
        }
    }
}

// Kernel D: merge NSPLIT j-splits, divide by l, write out[n][h*64+o]
__global__ __launch_bounds__(256) void k_merge(
    const float* __restrict__ ws_acc, const float* __restrict__ ws_l,
    float* __restrict__ out)
{
    const int idx = blockIdx.x * 256 + threadIdx.x;
    const int o = idx & 63;
    const int h = (idx >> 6) & 3;
    const int n = idx >> 8;
    const int ib = n >> 4, r = n & 15;
    float l = 0.f, v = 0.f;
    #pragma unroll
    for (int s = 0; s < NSPLIT; ++s) {
        const int w = ((ib * NSPLIT + s) * NH + h) * 16 + r;
        l += ws_l[w];
        v += ws_acc[(size_t)w * 64 + o];
    }
    out[idx] = v / l;
}

extern "C" void kernel_launch(void* const* d_in, const int* in_sizes, int n_in,
                              void* d_out, int out_size, void* d_ws, size_t ws_size,
                              hipStream_t stream) {
    (void)in_sizes; (void)n_in; (void)out_size; (void)ws_size;
    const float* x  = (const float*)d_in[0];
    const int*  adj = (const int*)d_in[1];
    const float* W  = (const float*)d_in[2];
    const float* a  = (const float*)d_in[3];
    float* out = (float*)d_out;
    char* ws = (char*)d_ws;

    size_t off = 0;
    short* WhT   = (short*)(ws + off); off += (size_t)NH * FOUT * NN * 2;   // 2 MB
    float* s1    = (float*)(ws + off); off += (size_t)NH * NN * 4;          // 64 KB
    float* s2    = (float*)(ws + off); off += (size_t)NH * NN * 4;          // 64 KB
    float* c1g   = (float*)(ws + off); off += (size_t)NH * NN * 4;          // 64 KB
    float* c2g   = (float*)(ws + off); off += (size_t)NH * NN * 4;          // 64 KB
    u64*   packed= (u64*)  (ws + off); off += (size_t)(NN / 64) * NN * 8;   // 2 MB
    float* ws_l  = (float*)(ws + off); off += (size_t)256 * NSPLIT * NH * 16 * 4;  // 256 KB
    float* ws_acc= (float*)(ws + off);                                      // 16.8 MB

    k_wh<<<dim3(64, 4), 256, 0, stream>>>(x, W, a, WhT, s1, s2);
    k_pack<<<4096, 256, 0, stream>>>(adj, packed);
    k_prep<<<NH * NN / 256, 256, 0, stream>>>(s1, s2, c1g, c2g);
    k_attn<<<dim3(64, NH, NSPLIT), 256, 0, stream>>>(packed, WhT, c1g, c2g, s2, ws_acc, ws_l);
    k_merge<<<4096, 256, 0, stream>>>(ws_acc, ws_l, out);
}